// Round 4
// baseline (114.969 us; speedup 1.0000x reference)
//
#include <hip/hip_runtime.h>
#include <math.h>

// Problem constants (fixed by reference setup_inputs)
#define N_TOT 8192
#define M_TOT 16384
#define EPS_N 1024
#define N_EMB 16

#define LOG2E 1.4426950408889634f
#define LN2   0.6931471805599453f
#define EXP2(x)   __builtin_amdgcn_exp2f(x)   // v_exp_f32
#define LOG2F_(x) __builtin_amdgcn_logf(x)    // v_log_f32 (log2)

// K1 tiling: product-grid factorization e_j = m_k + T*u_l  (j = k*1024 + l)
//   t_ij = A_ik + B_il,  P=2^A, Q=2^B, S_kl = sum_i P_ik Q_il
// 4 l's per lane: each 80B P-row broadcast feeds 64 FMAs (R3 was 32 -> LDS-pipe bound)
#define BLK1  512
#define IC    128                 // i's per block (8 waves x 16)
#define NICH  (N_TOT / IC)        // 64
#define LCH   256                 // l's per block
#define NLCH  (EPS_N / LCH)       // 4
#define NQ    (LCH / 64)          // 4 l's per lane

__global__ __launch_bounds__(BLK1) void gemm_partial_kernel(
    const float* __restrict__ z, const float* __restrict__ emb,
    const float* __restrict__ log_sigma, const float* __restrict__ eps,
    const float* __restrict__ temperature, float* __restrict__ part,
    unsigned int* __restrict__ counter)
{
    __shared__ __align__(16) float4 rows[IC * 5];       // 10 KB: 4x P-float4 + (T*b0,T*b1)
    __shared__ __align__(16) float  tile[N_EMB * LCH];  // 16 KB ds_add accumulation tile

    const int t  = threadIdx.x;
    const int l0 = blockIdx.x * LCH;
    const int ib = blockIdx.y;

    // zero K2's finalize counter (visible to K2 across the dispatch boundary)
    if (blockIdx.x == 0 && ib == 0 && t == 0) *counter = 0u;

    const float ls = log_sigma[0];
    const float T  = temperature[0];
    const float alpha = -0.5f * EXP2(LOG2E * (-2.0f * ls));  // -1/(2 sigma^2)
    const float La  = LOG2E * alpha;
    const float omT = 1.0f - T;

    // Phase A: stage P-rows (512 thr x 4 exps cover 128 i x 16 k) + zero tile
    {
        const int il = t & (IC - 1);
        const int kq = t >> 7;                  // 0..3 -> k = kq*4 .. kq*4+3
        const int i  = ib * IC + il;
        const float z0 = z[2 * i], z1 = z[2 * i + 1];
        const float c  = La * (z0 * z0 + z1 * z1);
        const float b0 = -2.0f * La * z0, b1 = -2.0f * La * z1;
        float4 p;
#pragma unroll
        for (int kk = 0; kk < 4; ++kk) {
            const int k = kq * 4 + kk;
            const float m0 = omT * emb[2 * k], m1 = omT * emb[2 * k + 1];
            ((float*)&p)[kk] = EXP2(c + b0 * m0 + b1 * m1);   // P_ik
        }
        rows[il * 5 + kq] = p;
        if (kq == 0) rows[il * 5 + 4] = make_float4(T * b0, T * b1, 0.0f, 0.0f);

        const float4 z4 = make_float4(0.0f, 0.0f, 0.0f, 0.0f);
        ((float4*)tile)[t * 2]     = z4;
        ((float4*)tile)[t * 2 + 1] = z4;
    }

    const int lane = t & 63;
    const int w    = t >> 6;                    // 8 waves, 16 i each
    const float2* eps2 = (const float2*)eps;
    float2 u[NQ];
#pragma unroll
    for (int q = 0; q < NQ; ++q) u[q] = eps2[l0 + lane + 64 * q];

    __syncthreads();

    float acc[N_EMB][NQ];
#pragma unroll
    for (int k = 0; k < N_EMB; ++k)
#pragma unroll
        for (int q = 0; q < NQ; ++q) acc[k][q] = 0.0f;

    const int ibase = w * (IC / 8);
    for (int n = 0; n < IC / 8; ++n) {
        const int ir = ibase + n;
        const float4 p0 = rows[ir * 5 + 0];     // wave-uniform broadcast reads
        const float4 p1 = rows[ir * 5 + 1];
        const float4 p2 = rows[ir * 5 + 2];
        const float4 p3 = rows[ir * 5 + 3];
        const float4 tb = rows[ir * 5 + 4];
        float qv[NQ];
#pragma unroll
        for (int q = 0; q < NQ; ++q)
            qv[q] = EXP2(fmaf(tb.y, u[q].y, tb.x * u[q].x));   // Q_il
        float pk[N_EMB];
        *(float4*)&pk[0]  = p0; *(float4*)&pk[4]  = p1;
        *(float4*)&pk[8]  = p2; *(float4*)&pk[12] = p3;
#pragma unroll
        for (int k = 0; k < N_EMB; ++k)
#pragma unroll
            for (int q = 0; q < NQ; ++q)
                acc[k][q] = fmaf(pk[k], qv[q], acc[k][q]);
    }

    // Phase C: cross-wave combine via LDS float atomics (ds_add_f32, conflict-free)
#pragma unroll
    for (int k = 0; k < N_EMB; ++k)
#pragma unroll
        for (int q = 0; q < NQ; ++q)
            atomicAdd(&tile[k * LCH + lane + 64 * q], acc[k][q]);
    __syncthreads();

    // write this block's 16 x 256 partial to global (coalesced float4 stores)
    {
        const int base = t * 8;
        const int k  = base >> 8;               // / LCH
        const int lo = base & (LCH - 1);
        float* dst = part + (size_t)ib * M_TOT + k * EPS_N + l0 + lo;
        ((float4*)dst)[0] = ((float4*)tile)[t * 2];
        ((float4*)dst)[1] = ((float4*)tile)[t * 2 + 1];
    }
}

// K2: combine partials, v_j = g_j + log2(S_j); block scalar; last block finalizes loss
#define BLK2 256
__global__ __launch_bounds__(BLK2) void reduce_final_kernel(
    const float* __restrict__ emb, const float* __restrict__ log_sigma,
    const float* __restrict__ eps, const float* __restrict__ temperature,
    const float* __restrict__ part, float* __restrict__ sc,
    unsigned int* __restrict__ counter, float* __restrict__ out)
{
    const int t = threadIdx.x;
    const int j = blockIdx.x * BLK2 + t;
    const float ls = log_sigma[0];
    const float T  = temperature[0];
    const float alpha = -0.5f * EXP2(LOG2E * (-2.0f * ls));

    float S = 0.0f;
#pragma unroll 8
    for (int ib = 0; ib < NICH; ++ib)
        S += part[(size_t)ib * M_TOT + j];      // coalesced across threads

    const int k = j >> 10, l = j & (EPS_N - 1);
    const float omT = 1.0f - T;
    const float e0 = omT * emb[2 * k]     + T * eps[2 * l];
    const float e1 = omT * emb[2 * k + 1] + T * eps[2 * l + 1];
    const float g  = LOG2E * alpha * (e0 * e0 + e1 * e1);   // factored-out 2^g

    float v = g + LOG2F_(S);                    // lse_j / ln2

#pragma unroll
    for (int off = 32; off; off >>= 1) v += __shfl_down(v, off, 64);
    __shared__ float wsum[BLK2 / 64];
    const int lane = t & 63, w = t >> 6;
    if (lane == 0) wsum[w] = v;
    __syncthreads();

    __shared__ int is_last;
    if (t == 0) {
        sc[blockIdx.x] = wsum[0] + wsum[1] + wsum[2] + wsum[3];
        __threadfence();                        // release block scalar
        unsigned int old = atomicAdd(counter, 1u);
        is_last = (old == (unsigned)(M_TOT / BLK2 - 1));
    }
    __syncthreads();

    if (is_last && t < 64) {
        __threadfence();                        // acquire other blocks' scalars
        float x = sc[t];                        // exactly 64 block scalars
#pragma unroll
        for (int off = 32; off; off >>= 1) x += __shfl_down(x, off, 64);
        if (t == 0) {
            const float sum_lse = x * LN2;
            // loss = -mean(lse) + 0.5*z_dim*(2*ls - 1) + log(n);  z_dim=2, n=8192
            out[0] = -sum_lse / (float)M_TOT + (2.0f * ls - 1.0f) + 9.010913347279288f;
        }
    }
}

extern "C" void kernel_launch(void* const* d_in, const int* in_sizes, int n_in,
                              void* d_out, int out_size, void* d_ws, size_t ws_size,
                              hipStream_t stream)
{
    const float* z    = (const float*)d_in[0];
    const float* emb  = (const float*)d_in[1];
    const float* lsig = (const float*)d_in[2];
    const float* eps  = (const float*)d_in[3];
    const float* temp = (const float*)d_in[4];

    float*        part    = (float*)d_ws;                    // 64 x 16384 floats = 4 MB
    float*        sc      = part + (size_t)NICH * M_TOT;     // 64 floats
    unsigned int* counter = (unsigned int*)(sc + 64);        // 1 uint (zeroed by K1)

    dim3 grid1(NLCH, NICH);                                  // 4 x 64 = 256 blocks
    gemm_partial_kernel<<<grid1, BLK1, 0, stream>>>(z, emb, lsig, eps, temp, part, counter);
    reduce_final_kernel<<<M_TOT / BLK2, BLK2, 0, stream>>>(emb, lsig, eps, temp, part, sc,
                                                           counter, (float*)d_out);
}